// Round 1
// baseline (212.004 us; speedup 1.0000x reference)
//
#include <hip/hip_runtime.h>
#include <hip/hip_bf16.h>

#define NT 4096      // H*W
#define CF 256       // feature channels
// CQK = 64

typedef __attribute__((ext_vector_type(8))) short bf16x8;
typedef __attribute__((ext_vector_type(4))) float f32x4;
typedef __attribute__((ext_vector_type(4))) short s16x4;

__device__ __forceinline__ short f2bf(float f) {
  union { float f; unsigned u; } v; v.f = f;
  unsigned r = v.u + 0x7FFFu + ((v.u >> 16) & 1u);   // RTNE
  return (short)(r >> 16);
}

// ---------------------------------------------------------------------------
// Projection: Y[i,o] = (sum_c X[c,i] * W[o,c] + bias[o]) * scale, bf16 output.
// TRANS=false -> Y (B,NT,O) row-major;  TRANS=true -> Y (B,O,NT).
// Per block: one 64-row i-tile, full O. 4 waves; wave owns all 64 i-rows and
// an O/4 column slice (good B-operand reuse).
// ---------------------------------------------------------------------------
template<int O, bool TRANS>
__global__ __launch_bounds__(256, 2)
void proj_kernel(const float* __restrict__ X, const float* __restrict__ W,
                 const float* __restrict__ Bv, short* __restrict__ Y, float scale)
{
  __shared__ alignas(16) short Xlds[64 * 256];   // [i][c] bf16, XOR-swizzled
  const int tid = threadIdx.x;
  const int wv = tid >> 6, l = tid & 63;
  const int l15 = l & 15, l4 = l >> 4;
  const int i0 = blockIdx.x * 64;
  const int b  = blockIdx.y;
  const float* Xb = X + (size_t)b * CF * NT;

  // stage X[c][i0+i] -> Xlds[i][c] (transpose via packed 8B swizzled writes)
#pragma unroll
  for (int it = 0; it < 16; ++it) {
    int c0 = it * 16 + wv * 4;
    float x0 = Xb[(size_t)(c0 + 0) * NT + i0 + l];
    float x1 = Xb[(size_t)(c0 + 1) * NT + i0 + l];
    float x2 = Xb[(size_t)(c0 + 2) * NT + i0 + l];
    float x3 = Xb[(size_t)(c0 + 3) * NT + i0 + l];
    s16x4 pk; pk[0] = f2bf(x0); pk[1] = f2bf(x1); pk[2] = f2bf(x2); pk[3] = f2bf(x3);
    int phys = (l * 512 + c0 * 2) ^ ((l & 31) << 4);
    *(s16x4*)((char*)Xlds + phys) = pk;
  }
  __syncthreads();

  constexpr int NO = O / 64;          // o-frags per wave (1 for O=64, 4 for O=256)
  f32x4 acc[4][NO] = {};

#pragma unroll
  for (int kk = 0; kk < 8; ++kk) {
    bf16x8 a[4];
#pragma unroll
    for (int mi = 0; mi < 4; ++mi) {
      int i = 16 * mi + l15;
      int phys = (i * 512 + kk * 64 + l4 * 16) ^ ((i & 31) << 4);
      a[mi] = *(const bf16x8*)((const char*)Xlds + phys);
    }
#pragma unroll
    for (int no = 0; no < NO; ++no) {
      int o = wv * (O / 4) + 16 * no + l15;
      const float* wp = W + (size_t)o * CF + kk * 32 + l4 * 8;
      bf16x8 wf;
#pragma unroll
      for (int t = 0; t < 8; ++t) wf[t] = f2bf(wp[t]);
#pragma unroll
      for (int mi = 0; mi < 4; ++mi)
        acc[mi][no] = __builtin_amdgcn_mfma_f32_16x16x32_bf16(a[mi], wf, acc[mi][no], 0, 0, 0);
    }
  }

#pragma unroll
  for (int no = 0; no < NO; ++no) {
    int o = wv * (O / 4) + 16 * no + l15;
    float bv = Bv[o];
#pragma unroll
    for (int mi = 0; mi < 4; ++mi) {
      if (TRANS) {
        s16x4 pk;
#pragma unroll
        for (int r = 0; r < 4; ++r) pk[r] = f2bf((acc[mi][no][r] + bv) * scale);
        *(s16x4*)&Y[((size_t)b * O + o) * NT + i0 + 16 * mi + l4 * 4] = pk;
      } else {
#pragma unroll
        for (int r = 0; r < 4; ++r) {
          int i = i0 + 16 * mi + l4 * 4 + r;
          Y[((size_t)b * NT + i) * O + o] = f2bf((acc[mi][no][r] + bv) * scale);
        }
      }
    }
  }
}

// ---------------------------------------------------------------------------
// Flash attention + residual.
// Q (B,NT,64) bf16 (pre-scaled by 1/16), K (B,NT,64) bf16, Vt (B,256,NT) bf16.
// Block: 256 thr (4 waves), one 64-row q-tile, col-split via blockIdx.z
// (each wg produces 128 of the 256 output channels; softmax duplicated).
// Wave wv: softmax rows [16wv,16wv+16), output cols [cbase, cbase+32).
// ---------------------------------------------------------------------------
__global__ __launch_bounds__(256, 2)
void flash_kernel(const short* __restrict__ Q, const short* __restrict__ K,
                  const short* __restrict__ Vt, const float* __restrict__ src,
                  const float* __restrict__ gamma_p, float* __restrict__ out)
{
  __shared__ alignas(16) short Plds[64 * 64];     // P tile bf16, XOR-swizzled rows
  __shared__ alignas(16) float scale_lds[64];     // per-row rescale / final lsum
  __shared__ float Obuf[4][16][36];               // per-wave epilogue transpose

  const int tid = threadIdx.x;
  const int wv = tid >> 6, l = tid & 63;
  const int l15 = l & 15, l4 = l >> 4;
  const int i0 = blockIdx.x * 64;
  const int b  = blockIdx.y;
  const int cbase = blockIdx.z * 128 + wv * 32;

  const short* Qb = Q  + (size_t)b * NT * 64;
  const short* Kb = K  + (size_t)b * NT * 64;
  const short* Vb = Vt + (size_t)b * CF * NT;

  // Q fragments for this wave's 16 rows (A-operand: row=l15, k=l4*8..)
  bf16x8 qf[2];
#pragma unroll
  for (int kk = 0; kk < 2; ++kk)
    qf[kk] = *(const bf16x8*)&Qb[(size_t)(i0 + 16 * wv + l15) * 64 + kk * 32 + l4 * 8];

  // K fragments for key-tile 0 (B-operand: col=l15, k=l4*8..)
  bf16x8 kf[4][2];
#pragma unroll
  for (int nj = 0; nj < 4; ++nj)
#pragma unroll
    for (int kk = 0; kk < 2; ++kk)
      kf[nj][kk] = *(const bf16x8*)&Kb[(size_t)(16 * nj + l15) * 64 + kk * 32 + l4 * 8];

  f32x4 acc[4][2] = {};
  float mrow[4], lrow[4];
#pragma unroll
  for (int r = 0; r < 4; ++r) { mrow[r] = -3.0e38f; lrow[r] = 0.f; }

  for (int jb = 0; jb < 64; ++jb) {
    const int j0 = jb * 64;

    // S = Q @ K^T  (scale already folded into Q)
    f32x4 s[4];
#pragma unroll
    for (int nj = 0; nj < 4; ++nj) { f32x4 z = {0.f, 0.f, 0.f, 0.f}; s[nj] = z; }
#pragma unroll
    for (int kk = 0; kk < 2; ++kk)
#pragma unroll
      for (int nj = 0; nj < 4; ++nj)
        s[nj] = __builtin_amdgcn_mfma_f32_16x16x32_bf16(qf[kk], kf[nj][kk], s[nj], 0, 0, 0);

    // issue V loads (this tile) and K loads (next tile); latency hides under softmax
    bf16x8 vb[2][2];
#pragma unroll
    for (int nv = 0; nv < 2; ++nv)
#pragma unroll
      for (int kk = 0; kk < 2; ++kk)
        vb[nv][kk] = *(const bf16x8*)&Vb[(size_t)(cbase + 16 * nv + l15) * NT + j0 + kk * 32 + l4 * 8];
    if (jb < 63) {
#pragma unroll
      for (int nj = 0; nj < 4; ++nj)
#pragma unroll
        for (int kk = 0; kk < 2; ++kk)
          kf[nj][kk] = *(const bf16x8*)&Kb[(size_t)(j0 + 64 + 16 * nj + l15) * 64 + kk * 32 + l4 * 8];
    }

    // online softmax over this wave's 16 rows (16-lane-group shuffle reduce)
    float sc[4];
#pragma unroll
    for (int r = 0; r < 4; ++r) {
      float mx = fmaxf(fmaxf(s[0][r], s[1][r]), fmaxf(s[2][r], s[3][r]));
#pragma unroll
      for (int mk = 1; mk <= 8; mk <<= 1) mx = fmaxf(mx, __shfl_xor(mx, mk, 64));
      float mnew = fmaxf(mrow[r], mx);
      sc[r] = __expf(mrow[r] - mnew);
      mrow[r] = mnew;
      float rs = 0.f;
#pragma unroll
      for (int nj = 0; nj < 4; ++nj) {
        float p = __expf(s[nj][r] - mnew);
        s[nj][r] = p;
        rs += p;
      }
#pragma unroll
      for (int mk = 1; mk <= 8; mk <<= 1) rs += __shfl_xor(rs, mk, 64);
      lrow[r] = lrow[r] * sc[r] + rs;
    }

    // publish P (bf16, swizzled) and row rescale factors
#pragma unroll
    for (int r = 0; r < 4; ++r) {
      int q = 16 * wv + l4 * 4 + r;
#pragma unroll
      for (int nj = 0; nj < 4; ++nj) {
        int bo = ((q * 64 + l15 + 16 * nj) * 2) ^ ((q & 7) << 4);
        *(short*)((char*)Plds + bo) = f2bf(s[nj][r]);
      }
      if (l15 == 0) scale_lds[q] = sc[r];
    }
    __syncthreads();

    // rescale O by broadcast row scales (rows 16mi + l4*4 + r)
#pragma unroll
    for (int mi = 0; mi < 4; ++mi) {
      f32x4 s4 = *(const f32x4*)&scale_lds[16 * mi + l4 * 4];
#pragma unroll
      for (int nv = 0; nv < 2; ++nv)
#pragma unroll
        for (int r = 0; r < 4; ++r)
          acc[mi][nv][r] *= s4[r];
    }

    // O += P @ V   (A = P from LDS, B = Vt fragments)
#pragma unroll
    for (int kk = 0; kk < 2; ++kk) {
      bf16x8 pa[4];
#pragma unroll
      for (int mi = 0; mi < 4; ++mi) {
        int q = 16 * mi + l15;
        int bo = ((q * 64 + kk * 32 + l4 * 8) * 2) ^ ((q & 7) << 4);
        pa[mi] = *(const bf16x8*)((const char*)Plds + bo);
      }
#pragma unroll
      for (int nv = 0; nv < 2; ++nv)
#pragma unroll
        for (int mi = 0; mi < 4; ++mi)
          acc[mi][nv] = __builtin_amdgcn_mfma_f32_16x16x32_bf16(pa[mi], vb[nv][kk], acc[mi][nv], 0, 0, 0);
    }
    __syncthreads();
  }

  // share final row sums
#pragma unroll
  for (int r = 0; r < 4; ++r)
    if (l15 == 0) scale_lds[16 * wv + l4 * 4 + r] = lrow[r];
  __syncthreads();

  const float g = gamma_p[0];
  const float* srcb = src + (size_t)b * CF * NT;
  float* outb = out + (size_t)b * CF * NT;

  // epilogue: normalize, transpose via per-wave LDS, fused residual store
#pragma unroll
  for (int mi = 0; mi < 4; ++mi) {
    f32x4 lv = *(const f32x4*)&scale_lds[16 * mi + l4 * 4];
#pragma unroll
    for (int nv = 0; nv < 2; ++nv)
#pragma unroll
      for (int r = 0; r < 4; ++r)
        Obuf[wv][l4 * 4 + r][16 * nv + l15] = acc[mi][nv][r] / lv[r];
    __syncthreads();
#pragma unroll
    for (int it = 0; it < 8; ++it) {
      int cl = it * 4 + l4;
      int c  = cbase + cl;
      int i  = i0 + 16 * mi + l15;
      float v = Obuf[wv][l15][cl];
      size_t off = (size_t)c * NT + i;
      outb[off] = g * v + srcb[off];
    }
    __syncthreads();
  }
}

// ---------------------------------------------------------------------------
extern "C" void kernel_launch(void* const* d_in, const int* in_sizes, int n_in,
                              void* d_out, int out_size, void* d_ws, size_t ws_size,
                              hipStream_t stream) {
  const float* src    = (const float*)d_in[0];
  const float* ref    = (const float*)d_in[1];
  const float* w_src  = (const float*)d_in[2];
  const float* b_src  = (const float*)d_in[3];
  const float* w_ref  = (const float*)d_in[4];
  const float* b_ref  = (const float*)d_in[5];
  const float* w_gate = (const float*)d_in[6];
  const float* b_gate = (const float*)d_in[7];
  const float* gamma  = (const float*)d_in[8];
  float* out = (float*)d_out;

  // ws: Q (2MB) | K (2MB) | Vt (8MB), bf16 bits as short
  const size_t qk_elems = (size_t)4 * NT * 64;
  const size_t v_elems  = (size_t)4 * CF * NT;
  if (ws_size < (qk_elems * 2 + v_elems) * sizeof(short)) return;
  short* Qw = (short*)d_ws;
  short* Kw = Qw + qk_elems;
  short* Vw = Kw + qk_elems;

  dim3 blk(256);
  dim3 gp(NT / 64, 4);
  // fold energy scale c^-0.5 = 1/16 into the Q projection
  proj_kernel<64,  false><<<gp, blk, 0, stream>>>(src, w_src,  b_src,  Qw, 0.0625f);
  proj_kernel<64,  false><<<gp, blk, 0, stream>>>(ref, w_ref,  b_ref,  Kw, 1.0f);
  proj_kernel<256, true ><<<gp, blk, 0, stream>>>(ref, w_gate, b_gate, Vw, 1.0f);

  dim3 gf(NT / 64, 4, 2);   // q-tiles x batch x col-split
  flash_kernel<<<gf, blk, 0, stream>>>(Qw, Kw, Vw, src, gamma, out);
}